// Round 10
// baseline (871.630 us; speedup 1.0000x reference)
//
#include <hip/hip_runtime.h>
#include <hip/hip_bf16.h>

#define N_TOK 4096
#define DIM   1024
#define VOCAB 32000
#define BM 128
#define BN 128
#define BKB 64           // K-stage depth in BYTES; single-buffered -> 16 KB LDS total
#define SMOOTH 0.1f

typedef __attribute__((ext_vector_type(4))) float float4v;
typedef __attribute__((ext_vector_type(2))) long long2v;

// f32 -> fp8 e4m3 (OCP, HW cvt) for BOTH tensors in one dispatch.
// W is pre-scaled by 16 (2^4) to escape e4m3's subnormal range
// (|w| <= 0.0136 < 2^-6 min-normal); the GEMM epilogue folds 2^-4 back out.
// Numerics of this path harness-validated in R3-R9 (absmax 0.0).
__global__ void cvt_fp8_2(const float* __restrict__ a, unsigned* __restrict__ da, int n8a,
                          const float* __restrict__ b, unsigned* __restrict__ db, int n8b) {
  int i = blockIdx.x * blockDim.x + threadIdx.x;
  const float4* s; uint2* d; int j; float scl;
  if (i < n8a)            { s = (const float4*)a; d = (uint2*)da; j = i;        scl = 1.f;  }
  else if (i < n8a + n8b) { s = (const float4*)b; d = (uint2*)db; j = i - n8a;  scl = 16.f; }
  else return;
  float4 v0 = s[j * 2], v1 = s[j * 2 + 1];
  unsigned lo = 0, hi = 0;
  lo = __builtin_amdgcn_cvt_pk_fp8_f32(v0.x * scl, v0.y * scl, lo, false);
  lo = __builtin_amdgcn_cvt_pk_fp8_f32(v0.z * scl, v0.w * scl, lo, true);
  hi = __builtin_amdgcn_cvt_pk_fp8_f32(v1.x * scl, v1.y * scl, hi, false);
  hi = __builtin_amdgcn_cvt_pk_fp8_f32(v1.z * scl, v1.w * scl, hi, true);
  uint2 o; o.x = lo; o.y = hi;
  d[j] = o;
}

__device__ __forceinline__ void gload_lds16(const void* g, void* l) {
  __builtin_amdgcn_global_load_lds((const __attribute__((address_space(1))) unsigned int*)g,
                                   (__attribute__((address_space(3))) unsigned int*)l,
                                   16, 0, 0);
}

// logit[n, y_n] in exact f32: one wave per token row (keeps the NLL term at
// full precision independent of the fp8 GEMM path).
__global__ __launch_bounds__(256)
void tgt_dot(const float* __restrict__ x, const float* __restrict__ W,
             const int* __restrict__ y, float* __restrict__ tgtRow) {
  const int n = blockIdx.x * 4 + (threadIdx.x >> 6);
  const int lane = threadIdx.x & 63;
  const float4* xr = (const float4*)(x + (size_t)n * DIM);
  const float4* wr = (const float4*)(W + (size_t)y[n] * DIM);
  float d = 0.f;
#pragma unroll
  for (int i = 0; i < 4; ++i) {
    float4 a = xr[lane + 64 * i], b = wr[lane + 64 * i];
    d += a.x * b.x + a.y * b.y + a.z * b.z + a.w * b.w;
  }
#pragma unroll
  for (int off = 32; off > 0; off >>= 1) d += __shfl_xor(d, off, 64);
  if (lane == 0) tgtRow[n] = d;
}

// C = X8[4096,1024] * W8[32000,1024]^T (fp8 e4m3, mfma 16x16x32) with fused
// per-row sum(exp)/sum.
// R10 experiment: OCCUPANCY PROBE. All prior rounds used 32 KB LDS and sat
// at ~41% occupancy (~3.2 blocks/CU) regardless of launch_bounds (R9 proved
// the declared bound is not the limiter); m97-family data (32KB->3 blk,
// 64KB->2 blk) suggests an effective-LDS residency limit. This kernel halves
// LDS to 16 KB: BKB=64, single-buffered, 16 stages — otherwise the proven R7
// frame verbatim (2-barrier loop, 2D grid(32,250) x-fastest, zero-conflict
// swizzle). The 64-B-row swizzle (stored cb c at row r holds global
// c ^ ((r>>1)&3); reader slot quad^((r16>>1)&3)) measured ZERO conflicts in
// R8. k-bijection k = 16*quad + 8*m + b shared by A and B (validated R5-R9).
// Pre-committed read: occupancy up + time down => LDS-residency confirmed;
// occupancy flat + time up (R8-like barrier-doubling cost) => revert to R7.
// W pre-scaled x16; epilogue multiplies acc by 2^-4.
__global__ __launch_bounds__(256, 6)
void gemm_ce(const unsigned char* __restrict__ X8, const unsigned char* __restrict__ W8,
             float* __restrict__ rowExp, float* __restrict__ rowSum) {
  __shared__ __align__(16) unsigned char As[BM * BKB];  // 8 KB, [128][64B]
  __shared__ __align__(16) unsigned char Bs[BN * BKB];  // 8 KB -> 16 KB total

  const int ib = blockIdx.x;   // token tile (32)
  const int jb = blockIdx.y;   // vocab tile (250)
  const int row0 = ib * BM;
  const int col0 = jb * BN;

  const int tid  = threadIdx.x;
  const int wv   = tid >> 6;
  const int lane = tid & 63;
  const int wr = wv >> 1, wc = wv & 1;
  const int quad = lane >> 4;
  const int r16  = lane & 15;
  // staging map (R8-proven, 0 conflicts): 1 KB per inst = 16 rows x 4
  // colblocks; LDS dest linear at base+lane*16; lane FETCHES global
  // colblock (lane&3) ^ ((lane>>3)&3)  [= (slab-row>>1)&3].
  const int lrow4 = lane >> 2;                        // row within 16-row slab
  const int gcb4  = (lane & 3) ^ ((lane >> 3) & 3);   // pre-swizzled source cb
  const int s4    = (r16 >> 1) & 3;                   // reader's swizzle class

  const unsigned char* pAx = X8 + (size_t)(row0 + wv * 16 + lrow4) * DIM + gcb4 * 16;
  const unsigned char* pBx = W8 + (size_t)(col0 + wv * 16 + lrow4) * DIM + gcb4 * 16;

  float4v acc[4][4];
#pragma unroll
  for (int i = 0; i < 4; ++i)
#pragma unroll
    for (int j = 0; j < 4; ++j) acc[i][j] = (float4v){0.f, 0.f, 0.f, 0.f};

  const int cbOff = (quad ^ s4) * 16;   // stored slot of global cb = quad

  for (int kt = 0; kt < DIM / BKB; ++kt) {   // 16 stages
    __syncthreads();   // prior ds_reads done before overwrite
    // per wave: 2 A-slabs (rows wv*16, 64+wv*16) + 2 B-slabs = 4 gload_lds
    gload_lds16(pAx + kt * BKB,            &As[(wv * 16) * BKB]);
    gload_lds16(pAx + 64 * DIM + kt * BKB, &As[(64 + wv * 16) * BKB]);
    gload_lds16(pBx + kt * BKB,            &Bs[(wv * 16) * BKB]);
    gload_lds16(pBx + 64 * DIM + kt * BKB, &Bs[(64 + wv * 16) * BKB]);
    __syncthreads();   // staging visible (vmcnt drain)

    long2v bf[4];
#pragma unroll
    for (int j = 0; j < 4; ++j)
      bf[j] = *(const long2v*)&Bs[(wc * 64 + j * 16 + r16) * BKB + cbOff];
#pragma unroll
    for (int i = 0; i < 4; ++i) {
      const long2v af = *(const long2v*)&As[(wr * 64 + i * 16 + r16) * BKB + cbOff];
#pragma unroll
      for (int j = 0; j < 4; ++j) {
        acc[i][j] = __builtin_amdgcn_mfma_f32_16x16x32_fp8_fp8(af.x, bf[j].x, acc[i][j], 0, 0, 0);
        acc[i][j] = __builtin_amdgcn_mfma_f32_16x16x32_fp8_fp8(af.y, bf[j].y, acc[i][j], 0, 0, 0);
      }
    }
  }

  // Fused epilogue (proven R0 version): per-row sum(exp(logit)), sum(logit).
  // C/D layout: col = r16, row = quad*4 + reg (within each 16x16 tile).
  // acc carries W's x16 prescale -> fold out 2^-4 here.
#pragma unroll
  for (int i = 0; i < 4; ++i)
#pragma unroll
    for (int r = 0; r < 4; ++r) {
      float se = 0.f, ss = 0.f;
#pragma unroll
      for (int j = 0; j < 4; ++j) {
        const float v = acc[i][j][r] * 0.0625f;
        ss += v;
        se += __expf(v);
      }
#pragma unroll
      for (int off = 1; off < 16; off <<= 1) {
        se += __shfl_xor(se, off, 64);
        ss += __shfl_xor(ss, off, 64);
      }
      if (r16 == 0) {
        const int rloc = wr * 64 + i * 16 + quad * 4 + r;
        atomicAdd(&rowExp[row0 + rloc], se);
        atomicAdd(&rowSum[row0 + rloc], ss);
      }
    }
}

// loss = (1/N) sum lse - (1-s)/N * sum tgt - s/(N*V) * sum(all logits)
__global__ void finalize_kernel(const float* __restrict__ rowExp, const float* __restrict__ rowSum,
                                const float* __restrict__ tgtRow, float* __restrict__ out) {
  __shared__ float s1[256], s2[256], s3[256];
  const int t = threadIdx.x;
  float a = 0.f, b = 0.f, c = 0.f;
  for (int n = t; n < N_TOK; n += 256) {
    a += logf(rowExp[n]);
    b += rowSum[n];
    c += tgtRow[n];
  }
  s1[t] = a; s2[t] = b; s3[t] = c;
  __syncthreads();
  for (int o = 128; o > 0; o >>= 1) {
    if (t < o) { s1[t] += s1[t + o]; s2[t] += s2[t + o]; s3[t] += s3[t + o]; }
    __syncthreads();
  }
  if (t == 0) {
    const float inviN = 1.0f / (float)N_TOK;
    out[0] = s1[0] * inviN
           - (1.0f - SMOOTH) * s3[0] * inviN
           - SMOOTH * s2[0] / ((float)N_TOK * (float)VOCAB);
  }
}

extern "C" void kernel_launch(void* const* d_in, const int* in_sizes, int n_in,
                              void* d_out, int out_size, void* d_ws, size_t ws_size,
                              hipStream_t stream) {
  const float* x = (const float*)d_in[0];
  const float* W = (const float*)d_in[1];
  const int*   y = (const int*)d_in[2];
  float* out = (float*)d_out;

  char* ws = (char*)d_ws;
  float* rowExp = (float*)(ws);              // 4096 f32
  float* rowSum = (float*)(ws + 16384);      // 4096 f32
  float* tgtRow = (float*)(ws + 32768);      // 4096 f32 (fully written, no memset)
  unsigned char* X8 = (unsigned char*)(ws + 65536);                          // 4.2 MB
  unsigned char* W8 = (unsigned char*)(ws + 65536 + (size_t)N_TOK * DIM);    // 32.8 MB

  hipMemsetAsync(ws, 0, 32768, stream);  // zero rowExp/rowSum (ws poisoned 0xAA)

  tgt_dot<<<N_TOK / 4, 256, 0, stream>>>(x, W, y, tgtRow);

  const int n8x = N_TOK * DIM / 8, n8w = VOCAB * DIM / 8;
  cvt_fp8_2<<<(n8x + n8w + 255) / 256, 256, 0, stream>>>(x, (unsigned*)X8, n8x, W, (unsigned*)W8, n8w);

  dim3 grid(N_TOK / BM, VOCAB / BN);  // (32, 250): token-fastest for XCD locality
  gemm_ce<<<grid, 256, 0, stream>>>(X8, W8, rowExp, rowSum);

  finalize_kernel<<<1, 256, 0, stream>>>(rowExp, rowSum, tgtRow, out);
}